// Round 1
// baseline (1158.400 us; speedup 1.0000x reference)
//
#include <hip/hip_runtime.h>
#include <math.h>

#define N_NODES 4096
#define NFEAT 1870
#define HID 256
#define EMB 16

// ---------------------------------------------------------------------------
// Generic 64x64-tile fp32 GEMM: C = A(MxK) * B(KxN), optional ELU epilogue.
// block = 256 threads (16x16), each thread 4x4 micro-tile, BK=16.
// ---------------------------------------------------------------------------
template <int ACT> // 0 = none, 1 = elu
__global__ __launch_bounds__(256) void gemm_tile(
    const float* __restrict__ A, int lda,
    const float* __restrict__ B, int ldb,
    float* __restrict__ C, int ldc,
    int M, int N, int K)
{
    __shared__ float As[16][64];
    __shared__ float Bs[16][64];
    const int tid = threadIdx.x;
    const int tx = tid & 15, ty = tid >> 4;
    const int row0 = blockIdx.x * 64;
    const int col0 = blockIdx.y * 64;

    float acc[4][4] = {};
    const int nkt = (K + 15) >> 4;
    for (int kt = 0; kt < nkt; ++kt) {
        const int k0 = kt << 4;
#pragma unroll
        for (int i = 0; i < 4; ++i) {
            int idx = tid * 4 + i;           // 1024 elems of A tile
            int r = idx >> 4, kk = idx & 15;
            int k = k0 + kk;
            As[kk][r] = (k < K) ? A[(size_t)(row0 + r) * lda + k] : 0.f;
        }
#pragma unroll
        for (int i = 0; i < 4; ++i) {
            int idx = tid + i * 256;         // 1024 elems of B tile
            int kk = idx >> 6, c = idx & 63;
            int k = k0 + kk;
            Bs[kk][c] = (k < K) ? B[(size_t)k * ldb + col0 + c] : 0.f;
        }
        __syncthreads();
#pragma unroll
        for (int kk = 0; kk < 16; ++kk) {
            float4 a4 = *reinterpret_cast<const float4*>(&As[kk][ty * 4]);
            float4 b4 = *reinterpret_cast<const float4*>(&Bs[kk][tx * 4]);
            float av[4] = {a4.x, a4.y, a4.z, a4.w};
            float bv[4] = {b4.x, b4.y, b4.z, b4.w};
#pragma unroll
            for (int i = 0; i < 4; ++i)
#pragma unroll
                for (int j = 0; j < 4; ++j)
                    acc[i][j] += av[i] * bv[j];
        }
        __syncthreads();
    }
#pragma unroll
    for (int i = 0; i < 4; ++i) {
        int r = row0 + ty * 4 + i;
        float4 o;
        float v[4];
#pragma unroll
        for (int j = 0; j < 4; ++j) {
            float t = acc[i][j];
            if (ACT == 1) t = (t > 0.f) ? t : (expf(t) - 1.f);
            v[j] = t;
        }
        o.x = v[0]; o.y = v[1]; o.z = v[2]; o.w = v[3];
        *reinterpret_cast<float4*>(&C[(size_t)r * ldc + col0 + tx * 4]) = o;
    }
}

// ---------------------------------------------------------------------------
// fs[i] = h[i,:] . a_self ; fn[i] = h[i,:] . a_neigh.  One wave per row.
// ---------------------------------------------------------------------------
__global__ __launch_bounds__(256) void fvec_kernel(
    const float* __restrict__ h, int D,
    const float* __restrict__ a_s, const float* __restrict__ a_n,
    float* __restrict__ fs, float* __restrict__ fn, int nrows)
{
    const int wv = threadIdx.x >> 6;
    const int lane = threadIdx.x & 63;
    const int row = blockIdx.x * 4 + wv;
    if (row >= nrows) return;
    float s = 0.f, n = 0.f;
    for (int d = lane; d < D; d += 64) {
        float v = h[(size_t)row * D + d];
        s += v * a_s[d];
        n += v * a_n[d];
    }
#pragma unroll
    for (int off = 32; off > 0; off >>= 1) {
        s += __shfl_down(s, off, 64);
        n += __shfl_down(n, off, 64);
    }
    if (lane == 0) { fs[row] = s; fn[row] = n; }
}

// ---------------------------------------------------------------------------
// Per-row masked leaky-relu + softmax.  One block (256 thr) per row,
// e-row staged in LDS (16 KB).  att[i][j] written normalized.
// ---------------------------------------------------------------------------
__global__ __launch_bounds__(256) void att_row_kernel(
    const float* __restrict__ Mmat, const float* __restrict__ adj,
    const float* __restrict__ fs, const float* __restrict__ fn,
    float* __restrict__ att)
{
    __shared__ float e_s[N_NODES];
    __shared__ float wred[4];
    __shared__ float wsum[4];
    const int row = blockIdx.x;
    const int tid = threadIdx.x;
    const int lane = tid & 63, wv = tid >> 6;
    const float fsi = fs[row];

    float lmax = -3.0e38f;
#pragma unroll
    for (int t = 0; t < 16; ++t) {
        int j = t * 256 + tid;
        float m = Mmat[(size_t)row * N_NODES + j];
        float a = adj[(size_t)row * N_NODES + j];
        float e = (fsi + fn[j]) * m;
        e = (e > 0.f) ? e : 0.2f * e;      // leaky_relu, slope 0.2
        e = (a > 0.f) ? e : -9e15f;
        e_s[j] = e;
        lmax = fmaxf(lmax, e);
    }
#pragma unroll
    for (int off = 32; off > 0; off >>= 1)
        lmax = fmaxf(lmax, __shfl_down(lmax, off, 64));
    if (lane == 0) wred[wv] = lmax;
    __syncthreads();
    const float m = fmaxf(fmaxf(wred[0], wred[1]), fmaxf(wred[2], wred[3]));

    float lsum = 0.f;
#pragma unroll
    for (int t = 0; t < 16; ++t) {
        int j = t * 256 + tid;
        float p = expf(e_s[j] - m);
        e_s[j] = p;
        lsum += p;
    }
#pragma unroll
    for (int off = 32; off > 0; off >>= 1)
        lsum += __shfl_down(lsum, off, 64);
    if (lane == 0) wsum[wv] = lsum;
    __syncthreads();
    const float inv = 1.f / (wsum[0] + wsum[1] + wsum[2] + wsum[3]);
#pragma unroll
    for (int t = 0; t < 16; ++t) {
        int j = t * 256 + tid;
        att[(size_t)row * N_NODES + j] = e_s[j] * inv;
    }
}

// ---------------------------------------------------------------------------
// h2 = g1(4096x256) @ W2(256x16).  Block = 16 rows x 16 cols, LDS staged.
// ---------------------------------------------------------------------------
__global__ __launch_bounds__(256) void gemm_h2_kernel(
    const float* __restrict__ g1, const float* __restrict__ W2,
    float* __restrict__ h2)
{
    __shared__ float Ws[256][16];
    __shared__ float Gs[16][257];
    const int tid = threadIdx.x;
    const int row0 = blockIdx.x * 16;
#pragma unroll
    for (int i = 0; i < 16; ++i) {
        int idx = tid + i * 256;            // k = idx/16, c = idx%16
        Ws[idx >> 4][idx & 15] = W2[idx];
    }
#pragma unroll
    for (int i = 0; i < 16; ++i) {
        int idx = tid + i * 256;            // r = idx/256, k = idx%256
        Gs[idx >> 8][idx & 255] = g1[(size_t)(row0 + (idx >> 8)) * HID + (idx & 255)];
    }
    __syncthreads();
    const int r = tid >> 4, c = tid & 15;
    float acc = 0.f;
#pragma unroll 8
    for (int k = 0; k < 256; ++k)
        acc += Gs[r][k] * Ws[k][c];
    h2[(size_t)(row0 + r) * EMB + c] = acc;
}

// ---------------------------------------------------------------------------
// g2 = elu(att2(4096x4096) @ h2(4096x16)).  32 rows/block, BK=128.
// ---------------------------------------------------------------------------
__global__ __launch_bounds__(256) void gemm_att_h2_kernel(
    const float* __restrict__ att, const float* __restrict__ h2,
    float* __restrict__ g2)
{
    __shared__ float As[32][129];
    __shared__ float Hs[128][16];
    const int tid = threadIdx.x;
    const int row0 = blockIdx.x * 32;
    const int r = tid >> 3;        // 0..31
    const int cg = tid & 7;        // 2 cols each
    float acc0 = 0.f, acc1 = 0.f;
    for (int kt = 0; kt < 32; ++kt) {
        const int k0 = kt * 128;
#pragma unroll
        for (int i = 0; i < 16; ++i) {
            int idx = tid + i * 256;  // rr = idx/128, kk = idx%128
            As[idx >> 7][idx & 127] =
                att[(size_t)(row0 + (idx >> 7)) * N_NODES + k0 + (idx & 127)];
        }
#pragma unroll
        for (int i = 0; i < 8; ++i) {
            int idx = tid + i * 256;  // kk = idx/16, c = idx%16
            Hs[idx >> 4][idx & 15] = h2[(size_t)(k0 + (idx >> 4)) * EMB + (idx & 15)];
        }
        __syncthreads();
#pragma unroll 16
        for (int kk = 0; kk < 128; ++kk) {
            float a = As[r][kk];
            float2 hh = *reinterpret_cast<const float2*>(&Hs[kk][cg * 2]);
            acc0 += a * hh.x;
            acc1 += a * hh.y;
        }
        __syncthreads();
    }
    float v0 = (acc0 > 0.f) ? acc0 : (expf(acc0) - 1.f);
    float v1 = (acc1 > 0.f) ? acc1 : (expf(acc1) - 1.f);
    float2 o; o.x = v0; o.y = v1;
    *reinterpret_cast<float2*>(&g2[(size_t)(row0 + r) * EMB + cg * 2]) = o;
}

// ---------------------------------------------------------------------------
// z = g2 / max(||g2||_2, 1e-12) per row.  One thread per row.
// ---------------------------------------------------------------------------
__global__ __launch_bounds__(256) void normalize_kernel(
    const float* __restrict__ g2, float* __restrict__ z)
{
    const int row = blockIdx.x * 256 + threadIdx.x;
    const float4* src = reinterpret_cast<const float4*>(&g2[(size_t)row * EMB]);
    float4 v[4];
    float ss = 0.f;
#pragma unroll
    for (int i = 0; i < 4; ++i) {
        v[i] = src[i];
        ss += v[i].x * v[i].x + v[i].y * v[i].y + v[i].z * v[i].z + v[i].w * v[i].w;
    }
    const float inv = 1.f / fmaxf(sqrtf(ss), 1e-12f);
    float4* dst = reinterpret_cast<float4*>(&z[(size_t)row * EMB]);
#pragma unroll
    for (int i = 0; i < 4; ++i) {
        float4 o; o.x = v[i].x * inv; o.y = v[i].y * inv;
        o.z = v[i].z * inv; o.w = v[i].w * inv;
        dst[i] = o;
    }
}

// ---------------------------------------------------------------------------
// A_pred = sigmoid(z @ z^T).  64x64 tile per block, K=16 fully unrolled.
// ---------------------------------------------------------------------------
__global__ __launch_bounds__(256) void apred_kernel(
    const float* __restrict__ z, float* __restrict__ out)
{
    __shared__ float zr[64][20];
    __shared__ float zc[64][20];
    const int tid = threadIdx.x;
    const int r0 = blockIdx.y * 64, c0 = blockIdx.x * 64;
#pragma unroll
    for (int i = 0; i < 4; ++i) {
        int idx = tid + i * 256;  // rr = idx/16, d = idx%16
        int rr = idx >> 4, d = idx & 15;
        zr[rr][d] = z[(size_t)(r0 + rr) * EMB + d];
        zc[rr][d] = z[(size_t)(c0 + rr) * EMB + d];
    }
    __syncthreads();
    const int tx = tid & 15, ty = tid >> 4;
    float rb[4][16], cb[4][16];
#pragma unroll
    for (int i = 0; i < 4; ++i)
#pragma unroll
        for (int d = 0; d < 16; ++d) {
            rb[i][d] = zr[ty * 4 + i][d];
            cb[i][d] = zc[tx * 4 + i][d];
        }
#pragma unroll
    for (int i = 0; i < 4; ++i) {
        float4 o;
        float v[4];
#pragma unroll
        for (int j = 0; j < 4; ++j) {
            float s = 0.f;
#pragma unroll
            for (int d = 0; d < 16; ++d) s += rb[i][d] * cb[j][d];
            v[j] = 1.f / (1.f + expf(-s));
        }
        o.x = v[0]; o.y = v[1]; o.z = v[2]; o.w = v[3];
        *reinterpret_cast<float4*>(
            &out[(size_t)(r0 + ty * 4 + i) * N_NODES + c0 + tx * 4]) = o;
    }
}

// ---------------------------------------------------------------------------
extern "C" void kernel_launch(void* const* d_in, const int* in_sizes, int n_in,
                              void* d_out, int out_size, void* d_ws, size_t ws_size,
                              hipStream_t stream)
{
    const float* x    = (const float*)d_in[0];
    const float* adj  = (const float*)d_in[1];
    const float* Mm   = (const float*)d_in[2];
    const float* W1   = (const float*)d_in[3];
    const float* a_s1 = (const float*)d_in[4];
    const float* a_n1 = (const float*)d_in[5];
    const float* W2   = (const float*)d_in[6];
    const float* a_s2 = (const float*)d_in[7];
    const float* a_n2 = (const float*)d_in[8];

    float* out = (float*)d_out;
    float* att = out;                                   // A_pred region doubles as att scratch
    float* z   = out + (size_t)N_NODES * N_NODES;

    float* ws  = (float*)d_ws;
    float* h1  = ws;                                    // 4096*256
    float* g1  = h1 + (size_t)N_NODES * HID;            // 4096*256
    float* h2  = g1 + (size_t)N_NODES * HID;            // 4096*16
    float* g2  = h2 + (size_t)N_NODES * EMB;            // 4096*16
    float* fs1 = g2 + (size_t)N_NODES * EMB;
    float* fn1 = fs1 + N_NODES;
    float* fs2 = fn1 + N_NODES;
    float* fn2 = fs2 + N_NODES;

    // ---- layer 1 ----
    gemm_tile<0><<<dim3(64, 4), 256, 0, stream>>>(x, NFEAT, W1, HID, h1, HID,
                                                  N_NODES, HID, NFEAT);
    fvec_kernel<<<1024, 256, 0, stream>>>(h1, HID, a_s1, a_n1, fs1, fn1, N_NODES);
    att_row_kernel<<<N_NODES, 256, 0, stream>>>(Mm, adj, fs1, fn1, att);
    gemm_tile<1><<<dim3(64, 4), 256, 0, stream>>>(att, N_NODES, h1, HID, g1, HID,
                                                  N_NODES, HID, N_NODES);

    // ---- layer 2 ----
    gemm_h2_kernel<<<256, 256, 0, stream>>>(g1, W2, h2);
    fvec_kernel<<<1024, 256, 0, stream>>>(h2, EMB, a_s2, a_n2, fs2, fn2, N_NODES);
    att_row_kernel<<<N_NODES, 256, 0, stream>>>(Mm, adj, fs2, fn2, att);
    gemm_att_h2_kernel<<<128, 256, 0, stream>>>(att, h2, g2);

    // ---- epilogue ----
    normalize_kernel<<<16, 256, 0, stream>>>(g2, z);
    apred_kernel<<<dim3(64, 64), 256, 0, stream>>>(z, out);
}

// Round 2
// 454.888 us; speedup vs baseline: 2.5466x; 2.5466x over previous
//
#include <hip/hip_runtime.h>
#include <math.h>

#define NN 4096
#define NFEAT 1870
#define KPAD 1920
#define HID 256
#define EMB 16

typedef __attribute__((ext_vector_type(8))) short bf16x8;
typedef __attribute__((ext_vector_type(4))) float f32x4;

__device__ __forceinline__ ushort f2bf(float f) {
    unsigned u = __builtin_bit_cast(unsigned, f);
    u += 0x7fffu + ((u >> 16) & 1u);
    return (ushort)(u >> 16);
}
__device__ __forceinline__ float bf2f(ushort h) {
    unsigned u = ((unsigned)h) << 16;
    return __builtin_bit_cast(float, u);
}

// ---------------------------------------------------------------------------
// bf16x2 split-precision MFMA GEMM. C_partial[chunk] = A[.,kbeg:kend] @ B.
// Tile 128x64, 4 waves (2x2), BK=32, split-K over blockIdx.z.
// A: either bf16 hi/lo planes [NN][lda] (A_PLANES=1) or fp32 [NN][lda] with
// on-the-fly hi/lo split (A_PLANES=0, supports K tail vs Kreal).
// B: always bf16 hi/lo planes, TRANSPOSED layout BT[N][ldb] (K-contiguous).
// ---------------------------------------------------------------------------
template <int A_PLANES>
__global__ __launch_bounds__(256) void gemm_bf16x2(
    const void* Ap, const ushort* Alo,
    const ushort* BTh, const ushort* BTl, int ldb,
    int lda, int Kreal, int CHUNK,
    float* Cpart, int Ncols)
{
    __shared__ ushort Ah[128 * 32];
    __shared__ ushort Al[128 * 32];
    __shared__ ushort Bh[64 * 32];
    __shared__ ushort Bl[64 * 32];

    const int tid = threadIdx.x;
    const int lane = tid & 63;
    const int w = tid >> 6;
    const int wr = w >> 1, wc = w & 1;
    const int row0 = blockIdx.x * 128;
    const int col0 = blockIdx.y * 64;
    const int kbeg = blockIdx.z * CHUNK;
    const int kend = min(Kreal, kbeg + CHUNK);
    const int nsteps = (kend - kbeg + 31) >> 5;

    const int ar = tid >> 1;        // A stage row 0..127
    const int as2 = (tid & 1) * 2;  // slots {0,1} or {2,3}
    const int br = tid >> 2;        // B stage row 0..63
    const int bs = tid & 3;         // slot 0..3

    const int fr = lane & 15;       // fragment row/col within 16
    const int fs = lane >> 4;       // k-slot 0..3

    f32x4 acc[4][2] = {};

    for (int ks = 0; ks < nsteps; ++ks) {
        const int k0 = kbeg + (ks << 5);
        // ---- stage A tile (128 x 32) ----
        if (A_PLANES) {
            const ushort* Ahg = (const ushort*)Ap;
            size_t base = (size_t)(row0 + ar) * lda + k0;
#pragma unroll
            for (int c = 0; c < 2; ++c) {
                int slot = as2 + c;
                int4 vh = *(const int4*)&Ahg[base + slot * 8];
                int4 vl = *(const int4*)&Alo[base + slot * 8];
                int off = ar * 32 + ((slot ^ ((ar >> 1) & 3)) << 3);
                *(int4*)&Ah[off] = vh;
                *(int4*)&Al[off] = vl;
            }
        } else {
            const float* Af = (const float*)Ap;
            size_t base = (size_t)(row0 + ar) * lda;
#pragma unroll
            for (int c = 0; c < 2; ++c) {
                int slot = as2 + c;
                int kk = k0 + slot * 8;
                float v[8];
                if (kk + 8 <= Kreal) {
#pragma unroll
                    for (int j = 0; j < 4; ++j) {
                        float2 t2 = *(const float2*)&Af[base + kk + j * 2];
                        v[j * 2] = t2.x; v[j * 2 + 1] = t2.y;
                    }
                } else {
#pragma unroll
                    for (int j = 0; j < 8; ++j)
                        v[j] = (kk + j < Kreal) ? Af[base + kk + j] : 0.f;
                }
                ushort hh[8], ll[8];
#pragma unroll
                for (int j = 0; j < 8; ++j) {
                    hh[j] = f2bf(v[j]);
                    ll[j] = f2bf(v[j] - bf2f(hh[j]));
                }
                int off = ar * 32 + ((slot ^ ((ar >> 1) & 3)) << 3);
                *(int4*)&Ah[off] = *(int4*)hh;
                *(int4*)&Al[off] = *(int4*)ll;
            }
        }
        // ---- stage B tile (64 cols x 32 k), from transposed planes ----
        {
            size_t base = (size_t)(col0 + br) * ldb + k0 + bs * 8;
            int4 vh = *(const int4*)&BTh[base];
            int4 vl = *(const int4*)&BTl[base];
            int off = br * 32 + ((bs ^ ((br >> 1) & 3)) << 3);
            *(int4*)&Bh[off] = vh;
            *(int4*)&Bl[off] = vl;
        }
        __syncthreads();
        // ---- fragments + MFMA ----
        bf16x8 afh[4], afl[4], bfh[2], bfl[2];
#pragma unroll
        for (int m = 0; m < 4; ++m) {
            int r = wr * 64 + m * 16 + fr;
            int off = r * 32 + ((fs ^ ((r >> 1) & 3)) << 3);
            afh[m] = *(const bf16x8*)&Ah[off];
            afl[m] = *(const bf16x8*)&Al[off];
        }
#pragma unroll
        for (int n = 0; n < 2; ++n) {
            int r = wc * 32 + n * 16 + fr;
            int off = r * 32 + ((fs ^ ((r >> 1) & 3)) << 3);
            bfh[n] = *(const bf16x8*)&Bh[off];
            bfl[n] = *(const bf16x8*)&Bl[off];
        }
#pragma unroll
        for (int m = 0; m < 4; ++m)
#pragma unroll
            for (int n = 0; n < 2; ++n) {
                acc[m][n] = __builtin_amdgcn_mfma_f32_16x16x32_bf16(afh[m], bfh[n], acc[m][n], 0, 0, 0);
                acc[m][n] = __builtin_amdgcn_mfma_f32_16x16x32_bf16(afh[m], bfl[n], acc[m][n], 0, 0, 0);
                acc[m][n] = __builtin_amdgcn_mfma_f32_16x16x32_bf16(afl[m], bfh[n], acc[m][n], 0, 0, 0);
            }
        __syncthreads();
    }
    // ---- write partial: C/D layout col=lane&15, row=(lane>>4)*4+reg ----
    float* Cp = Cpart + (size_t)blockIdx.z * NN * Ncols;
#pragma unroll
    for (int m = 0; m < 4; ++m)
#pragma unroll
        for (int n = 0; n < 2; ++n)
#pragma unroll
            for (int r = 0; r < 4; ++r) {
                int row = row0 + wr * 64 + m * 16 + fs * 4 + r;
                int col = col0 + wc * 32 + n * 16 + fr;
                Cp[(size_t)row * Ncols + col] = acc[m][n][r];
            }
}

// ---------------------------------------------------------------------------
// W1 [NFEAT][HID] fp32 -> W1T hi/lo planes [HID][KPAD] bf16, zero-padded K.
// ---------------------------------------------------------------------------
__global__ __launch_bounds__(256) void conv_w1t_kernel(
    const float* __restrict__ W1, ushort* __restrict__ Wh, ushort* __restrict__ Wl)
{
    __shared__ float t[64][65];
    const int tid = threadIdx.x;
    const int k0 = blockIdx.x * 64, n0 = blockIdx.y * 64;
    const int kk = tid >> 2, c4 = (tid & 3) * 16;
#pragma unroll
    for (int j = 0; j < 4; ++j) {
        int k = k0 + kk;
        float4 v = make_float4(0.f, 0.f, 0.f, 0.f);
        if (k < NFEAT) v = *(const float4*)&W1[(size_t)k * HID + n0 + c4 + j * 4];
        t[kk][c4 + j * 4 + 0] = v.x; t[kk][c4 + j * 4 + 1] = v.y;
        t[kk][c4 + j * 4 + 2] = v.z; t[kk][c4 + j * 4 + 3] = v.w;
    }
    __syncthreads();
    const int on = tid >> 2, ok4 = (tid & 3) * 16;
#pragma unroll
    for (int j = 0; j < 4; ++j) {
        ushort hh[4], ll[4];
#pragma unroll
        for (int i = 0; i < 4; ++i) {
            float v = t[ok4 + j * 4 + i][on];
            hh[i] = f2bf(v); ll[i] = f2bf(v - bf2f(hh[i]));
        }
        size_t o = (size_t)(n0 + on) * KPAD + k0 + ok4 + j * 4;
        *(ushort4*)&Wh[o] = *(ushort4*)hh;
        *(ushort4*)&Wl[o] = *(ushort4*)ll;
    }
}

// ---------------------------------------------------------------------------
// h1 = sum of 4 partials; also emit h1T hi/lo planes [HID][NN].
// ---------------------------------------------------------------------------
__global__ __launch_bounds__(256) void reduce_h1_kernel(
    const float* __restrict__ part, float* __restrict__ h1,
    ushort* __restrict__ Th, ushort* __restrict__ Tl)
{
    __shared__ float t[64][65];
    const int tid = threadIdx.x;
    const int r0 = blockIdx.x * 64, c0 = blockIdx.y * 64;
    const int tr = tid >> 2, tc4 = (tid & 3) * 16;
#pragma unroll
    for (int j = 0; j < 4; ++j) {
        size_t o = (size_t)(r0 + tr) * HID + c0 + tc4 + j * 4;
        float4 s = *(const float4*)&part[o];
#pragma unroll
        for (int ch = 1; ch < 4; ++ch) {
            float4 p = *(const float4*)&part[(size_t)ch * NN * HID + o];
            s.x += p.x; s.y += p.y; s.z += p.z; s.w += p.w;
        }
        *(float4*)&h1[o] = s;
        t[tr][tc4 + j * 4 + 0] = s.x; t[tr][tc4 + j * 4 + 1] = s.y;
        t[tr][tc4 + j * 4 + 2] = s.z; t[tr][tc4 + j * 4 + 3] = s.w;
    }
    __syncthreads();
    const int oc = tid >> 2, ok4 = (tid & 3) * 16;
#pragma unroll
    for (int j = 0; j < 4; ++j) {
        ushort hh[4], ll[4];
#pragma unroll
        for (int i = 0; i < 4; ++i) {
            float v = t[ok4 + j * 4 + i][oc];
            hh[i] = f2bf(v); ll[i] = f2bf(v - bf2f(hh[i]));
        }
        size_t o = (size_t)(c0 + oc) * NN + r0 + ok4 + j * 4;
        *(ushort4*)&Th[o] = *(ushort4*)hh;
        *(ushort4*)&Tl[o] = *(ushort4*)ll;
    }
}

// ---------------------------------------------------------------------------
// g1 = elu(sum of 4 partials)
// ---------------------------------------------------------------------------
__global__ __launch_bounds__(256) void reduce_g1_kernel(
    const float* __restrict__ part, float* __restrict__ g1)
{
    const int tid = threadIdx.x;
    const int r0 = blockIdx.x * 64, c0 = blockIdx.y * 64;
    const int tr = tid >> 2, tc4 = (tid & 3) * 16;
#pragma unroll
    for (int j = 0; j < 4; ++j) {
        size_t o = (size_t)(r0 + tr) * HID + c0 + tc4 + j * 4;
        float4 s = *(const float4*)&part[o];
#pragma unroll
        for (int ch = 1; ch < 4; ++ch) {
            float4 p = *(const float4*)&part[(size_t)ch * NN * HID + o];
            s.x += p.x; s.y += p.y; s.z += p.z; s.w += p.w;
        }
        s.x = (s.x > 0.f) ? s.x : expm1f(s.x);
        s.y = (s.y > 0.f) ? s.y : expm1f(s.y);
        s.z = (s.z > 0.f) ? s.z : expm1f(s.z);
        s.w = (s.w > 0.f) ? s.w : expm1f(s.w);
        *(float4*)&g1[o] = s;
    }
}

// ---------------------------------------------------------------------------
// fs[i] = h[i,:].a_self ; fn[i] = h[i,:].a_neigh.  One wave per row.
// ---------------------------------------------------------------------------
__global__ __launch_bounds__(256) void fvec_kernel(
    const float* __restrict__ h, int D,
    const float* __restrict__ a_s, const float* __restrict__ a_n,
    float* __restrict__ fs, float* __restrict__ fn, int nrows)
{
    const int wv = threadIdx.x >> 6;
    const int lane = threadIdx.x & 63;
    const int row = blockIdx.x * 4 + wv;
    if (row >= nrows) return;
    float s = 0.f, n = 0.f;
    for (int d = lane; d < D; d += 64) {
        float v = h[(size_t)row * D + d];
        s += v * a_s[d];
        n += v * a_n[d];
    }
#pragma unroll
    for (int off = 32; off > 0; off >>= 1) {
        s += __shfl_down(s, off, 64);
        n += __shfl_down(n, off, 64);
    }
    if (lane == 0) { fs[row] = s; fn[row] = n; }
}

// ---------------------------------------------------------------------------
// Per-row masked leaky-relu + softmax.  PLANES=1: write bf16 hi/lo planes;
// PLANES=0: write fp32 att.
// ---------------------------------------------------------------------------
template <int PLANES>
__global__ __launch_bounds__(256) void att_row_kernel(
    const float* __restrict__ Mmat, const float* __restrict__ adj,
    const float* __restrict__ fs, const float* __restrict__ fn,
    float* __restrict__ att_f32, ushort* __restrict__ att_hi,
    ushort* __restrict__ att_lo)
{
    __shared__ float e_s[NN];
    __shared__ float wred[4];
    __shared__ float wsum[4];
    const int row = blockIdx.x;
    const int tid = threadIdx.x;
    const int lane = tid & 63, wv = tid >> 6;
    const float fsi = fs[row];

    float lmax = -3.0e38f;
#pragma unroll
    for (int t = 0; t < 16; ++t) {
        int j = t * 256 + tid;
        float m = Mmat[(size_t)row * NN + j];
        float a = adj[(size_t)row * NN + j];
        float e = (fsi + fn[j]) * m;
        e = (e > 0.f) ? e : 0.2f * e;
        e = (a > 0.f) ? e : -9e15f;
        e_s[j] = e;
        lmax = fmaxf(lmax, e);
    }
#pragma unroll
    for (int off = 32; off > 0; off >>= 1)
        lmax = fmaxf(lmax, __shfl_down(lmax, off, 64));
    if (lane == 0) wred[wv] = lmax;
    __syncthreads();
    const float m = fmaxf(fmaxf(wred[0], wred[1]), fmaxf(wred[2], wred[3]));

    float lsum = 0.f;
#pragma unroll
    for (int t = 0; t < 16; ++t) {
        int j = t * 256 + tid;
        float p = expf(e_s[j] - m);
        e_s[j] = p;
        lsum += p;
    }
#pragma unroll
    for (int off = 32; off > 0; off >>= 1)
        lsum += __shfl_down(lsum, off, 64);
    if (lane == 0) wsum[wv] = lsum;
    __syncthreads();
    const float inv = 1.f / (wsum[0] + wsum[1] + wsum[2] + wsum[3]);
#pragma unroll
    for (int t = 0; t < 16; ++t) {
        int j = t * 256 + tid;
        float p = e_s[j] * inv;
        if (PLANES) {
            ushort h = f2bf(p);
            att_hi[(size_t)row * NN + j] = h;
            att_lo[(size_t)row * NN + j] = f2bf(p - bf2f(h));
        } else {
            att_f32[(size_t)row * NN + j] = p;
        }
    }
}

// ---------------------------------------------------------------------------
// h2 = g1(NNxHID) @ W2(HIDxEMB)
// ---------------------------------------------------------------------------
__global__ __launch_bounds__(256) void gemm_h2_kernel(
    const float* __restrict__ g1, const float* __restrict__ W2,
    float* __restrict__ h2)
{
    __shared__ float Ws[256][16];
    __shared__ float Gs[16][257];
    const int tid = threadIdx.x;
    const int row0 = blockIdx.x * 16;
#pragma unroll
    for (int i = 0; i < 16; ++i) {
        int idx = tid + i * 256;
        Ws[idx >> 4][idx & 15] = W2[idx];
    }
#pragma unroll
    for (int i = 0; i < 16; ++i) {
        int idx = tid + i * 256;
        Gs[idx >> 8][idx & 255] = g1[(size_t)(row0 + (idx >> 8)) * HID + (idx & 255)];
    }
    __syncthreads();
    const int r = tid >> 4, c = tid & 15;
    float acc = 0.f;
#pragma unroll 8
    for (int k = 0; k < 256; ++k)
        acc += Gs[r][k] * Ws[k][c];
    h2[(size_t)(row0 + r) * EMB + c] = acc;
}

// ---------------------------------------------------------------------------
// g2 = elu(att2(NNxNN fp32) @ h2(NNxEMB))
// ---------------------------------------------------------------------------
__global__ __launch_bounds__(256) void gemm_att_h2_kernel(
    const float* __restrict__ att, const float* __restrict__ h2,
    float* __restrict__ g2)
{
    __shared__ float As[32][129];
    __shared__ float Hs[128][16];
    const int tid = threadIdx.x;
    const int row0 = blockIdx.x * 32;
    const int r = tid >> 3;
    const int cg = tid & 7;
    float acc0 = 0.f, acc1 = 0.f;
    for (int kt = 0; kt < 32; ++kt) {
        const int k0 = kt * 128;
#pragma unroll
        for (int i = 0; i < 16; ++i) {
            int idx = tid + i * 256;
            As[idx >> 7][idx & 127] =
                att[(size_t)(row0 + (idx >> 7)) * NN + k0 + (idx & 127)];
        }
#pragma unroll
        for (int i = 0; i < 8; ++i) {
            int idx = tid + i * 256;
            Hs[idx >> 4][idx & 15] = h2[(size_t)(k0 + (idx >> 4)) * EMB + (idx & 15)];
        }
        __syncthreads();
#pragma unroll 16
        for (int kk = 0; kk < 128; ++kk) {
            float a = As[r][kk];
            float2 hh = *reinterpret_cast<const float2*>(&Hs[kk][cg * 2]);
            acc0 += a * hh.x;
            acc1 += a * hh.y;
        }
        __syncthreads();
    }
    float v0 = (acc0 > 0.f) ? acc0 : expm1f(acc0);
    float v1 = (acc1 > 0.f) ? acc1 : expm1f(acc1);
    float2 o; o.x = v0; o.y = v1;
    *reinterpret_cast<float2*>(&g2[(size_t)(row0 + r) * EMB + cg * 2]) = o;
}

// ---------------------------------------------------------------------------
__global__ __launch_bounds__(256) void normalize_kernel(
    const float* __restrict__ g2, float* __restrict__ z)
{
    const int row = blockIdx.x * 256 + threadIdx.x;
    const float4* src = reinterpret_cast<const float4*>(&g2[(size_t)row * EMB]);
    float4 v[4];
    float ss = 0.f;
#pragma unroll
    for (int i = 0; i < 4; ++i) {
        v[i] = src[i];
        ss += v[i].x * v[i].x + v[i].y * v[i].y + v[i].z * v[i].z + v[i].w * v[i].w;
    }
    const float inv = 1.f / fmaxf(sqrtf(ss), 1e-12f);
    float4* dst = reinterpret_cast<float4*>(&z[(size_t)row * EMB]);
#pragma unroll
    for (int i = 0; i < 4; ++i) {
        float4 o; o.x = v[i].x * inv; o.y = v[i].y * inv;
        o.z = v[i].z * inv; o.w = v[i].w * inv;
        dst[i] = o;
    }
}

// ---------------------------------------------------------------------------
__global__ __launch_bounds__(256) void apred_kernel(
    const float* __restrict__ z, float* __restrict__ out)
{
    __shared__ float zr[64][20];
    __shared__ float zc[64][20];
    const int tid = threadIdx.x;
    const int r0 = blockIdx.y * 64, c0 = blockIdx.x * 64;
#pragma unroll
    for (int i = 0; i < 4; ++i) {
        int idx = tid + i * 256;
        int rr = idx >> 4, d = idx & 15;
        zr[rr][d] = z[(size_t)(r0 + rr) * EMB + d];
        zc[rr][d] = z[(size_t)(c0 + rr) * EMB + d];
    }
    __syncthreads();
    const int tx = tid & 15, ty = tid >> 4;
    float rb[4][16], cb[4][16];
#pragma unroll
    for (int i = 0; i < 4; ++i)
#pragma unroll
        for (int d = 0; d < 16; ++d) {
            rb[i][d] = zr[ty * 4 + i][d];
            cb[i][d] = zc[tx * 4 + i][d];
        }
#pragma unroll
    for (int i = 0; i < 4; ++i) {
        float4 o;
        float v[4];
#pragma unroll
        for (int j = 0; j < 4; ++j) {
            float s = 0.f;
#pragma unroll
            for (int d = 0; d < 16; ++d) s += rb[i][d] * cb[j][d];
            v[j] = 1.f / (1.f + expf(-s));
        }
        o.x = v[0]; o.y = v[1]; o.z = v[2]; o.w = v[3];
        *reinterpret_cast<float4*>(
            &out[(size_t)(r0 + ty * 4 + i) * NN + c0 + tx * 4]) = o;
    }
}

// ---------------------------------------------------------------------------
extern "C" void kernel_launch(void* const* d_in, const int* in_sizes, int n_in,
                              void* d_out, int out_size, void* d_ws, size_t ws_size,
                              hipStream_t stream)
{
    const float* x    = (const float*)d_in[0];
    const float* adj  = (const float*)d_in[1];
    const float* Mm   = (const float*)d_in[2];
    const float* W1   = (const float*)d_in[3];
    const float* a_s1 = (const float*)d_in[4];
    const float* a_n1 = (const float*)d_in[5];
    const float* W2   = (const float*)d_in[6];
    const float* a_s2 = (const float*)d_in[7];
    const float* a_n2 = (const float*)d_in[8];

    float* out = (float*)d_out;
    // layer-1 att bf16 planes live in the A_pred region (exactly NN*NN*4 bytes)
    ushort* att_hi = (ushort*)d_out;
    ushort* att_lo = att_hi + (size_t)NN * NN;
    float*  att_f  = out;                       // layer-2 fp32 att, same region
    float*  z      = out + (size_t)NN * NN;

    char* w = (char*)d_ws;
    float* part  = (float*)w;  w += (size_t)4 * NN * HID * 4;   // 16.8 MB
    float* h1    = (float*)w;  w += (size_t)NN * HID * 4;
    float* g1    = (float*)w;  w += (size_t)NN * HID * 4;
    ushort* h1Th = (ushort*)w; w += (size_t)HID * NN * 2;
    ushort* h1Tl = (ushort*)w; w += (size_t)HID * NN * 2;
    ushort* W1Th = (ushort*)w; w += (size_t)HID * KPAD * 2;
    ushort* W1Tl = (ushort*)w; w += (size_t)HID * KPAD * 2;
    float* h2    = (float*)w;  w += (size_t)NN * EMB * 4;
    float* g2    = (float*)w;  w += (size_t)NN * EMB * 4;
    float* fs1   = (float*)w;  w += NN * 4;
    float* fn1   = (float*)w;  w += NN * 4;
    float* fs2   = (float*)w;  w += NN * 4;
    float* fn2   = (float*)w;  w += NN * 4;

    // ---- layer 1 ----
    conv_w1t_kernel<<<dim3(30, 4), 256, 0, stream>>>(W1, W1Th, W1Tl);
    gemm_bf16x2<0><<<dim3(32, 4, 4), 256, 0, stream>>>(
        x, nullptr, W1Th, W1Tl, KPAD, NFEAT, NFEAT, 480, part, HID);
    reduce_h1_kernel<<<dim3(64, 4), 256, 0, stream>>>(part, h1, h1Th, h1Tl);
    fvec_kernel<<<1024, 256, 0, stream>>>(h1, HID, a_s1, a_n1, fs1, fn1, NN);
    att_row_kernel<1><<<NN, 256, 0, stream>>>(Mm, adj, fs1, fn1, nullptr, att_hi, att_lo);
    gemm_bf16x2<1><<<dim3(32, 4, 4), 256, 0, stream>>>(
        att_hi, att_lo, h1Th, h1Tl, NN, NN, NN, 1024, part, HID);
    reduce_g1_kernel<<<dim3(64, 4), 256, 0, stream>>>(part, g1);

    // ---- layer 2 ----
    gemm_h2_kernel<<<256, 256, 0, stream>>>(g1, W2, h2);
    fvec_kernel<<<1024, 256, 0, stream>>>(h2, EMB, a_s2, a_n2, fs2, fn2, NN);
    att_row_kernel<0><<<NN, 256, 0, stream>>>(Mm, adj, fs2, fn2, att_f, nullptr, nullptr);
    gemm_att_h2_kernel<<<128, 256, 0, stream>>>(att_f, h2, g2);

    // ---- epilogue ----
    normalize_kernel<<<16, 256, 0, stream>>>(g2, z);
    apred_kernel<<<dim3(64, 64), 256, 0, stream>>>(z, out);
}

// Round 3
// 239.561 us; speedup vs baseline: 4.8355x; 1.8988x over previous
//
#include <hip/hip_runtime.h>
#include <math.h>

#define NN 4096
#define NFEAT 1870
#define KPAD 1920
#define HID 256
#define EMB 16

typedef __attribute__((ext_vector_type(8))) short bf16x8;
typedef __attribute__((ext_vector_type(4))) float f32x4;

__device__ __forceinline__ ushort f2bf(float f) {
    unsigned u = __builtin_bit_cast(unsigned, f);
    u += 0x7fffu + ((u >> 16) & 1u);
    return (ushort)(u >> 16);
}
__device__ __forceinline__ float bf2f(ushort h) {
    unsigned u = ((unsigned)h) << 16;
    return __builtin_bit_cast(float, u);
}

// ---------------------------------------------------------------------------
// bf16x2 split-precision MFMA GEMM. C_partial[chunk] = A[.,kbeg:kend] @ B.
// Tile 128x64, 4 waves (2x2), BK=32, split-K over blockIdx.z.
// ---------------------------------------------------------------------------
template <int A_PLANES>
__global__ __launch_bounds__(256) void gemm_bf16x2(
    const void* Ap, const ushort* Alo,
    const ushort* BTh, const ushort* BTl, int ldb,
    int lda, int Kreal, int CHUNK,
    float* Cpart, int Ncols)
{
    __shared__ ushort Ah[128 * 32];
    __shared__ ushort Al[128 * 32];
    __shared__ ushort Bh[64 * 32];
    __shared__ ushort Bl[64 * 32];

    const int tid = threadIdx.x;
    const int lane = tid & 63;
    const int w = tid >> 6;
    const int wr = w >> 1, wc = w & 1;
    const int row0 = blockIdx.x * 128;
    const int col0 = blockIdx.y * 64;
    const int kbeg = blockIdx.z * CHUNK;
    const int kend = min(Kreal, kbeg + CHUNK);
    const int nsteps = (kend - kbeg + 31) >> 5;

    const int ar = tid >> 1;
    const int as2 = (tid & 1) * 2;
    const int br = tid >> 2;
    const int bs = tid & 3;

    const int fr = lane & 15;
    const int fs = lane >> 4;

    f32x4 acc[4][2] = {};

    for (int ks = 0; ks < nsteps; ++ks) {
        const int k0 = kbeg + (ks << 5);
        if (A_PLANES) {
            const ushort* Ahg = (const ushort*)Ap;
            size_t base = (size_t)(row0 + ar) * lda + k0;
#pragma unroll
            for (int c = 0; c < 2; ++c) {
                int slot = as2 + c;
                int4 vh = *(const int4*)&Ahg[base + slot * 8];
                int4 vl = *(const int4*)&Alo[base + slot * 8];
                int off = ar * 32 + ((slot ^ ((ar >> 1) & 3)) << 3);
                *(int4*)&Ah[off] = vh;
                *(int4*)&Al[off] = vl;
            }
        } else {
            const float* Af = (const float*)Ap;
            size_t base = (size_t)(row0 + ar) * lda;
#pragma unroll
            for (int c = 0; c < 2; ++c) {
                int slot = as2 + c;
                int kk = k0 + slot * 8;
                float v[8];
                if (kk + 8 <= Kreal) {
#pragma unroll
                    for (int j = 0; j < 4; ++j) {
                        float2 t2 = *(const float2*)&Af[base + kk + j * 2];
                        v[j * 2] = t2.x; v[j * 2 + 1] = t2.y;
                    }
                } else {
#pragma unroll
                    for (int j = 0; j < 8; ++j)
                        v[j] = (kk + j < Kreal) ? Af[base + kk + j] : 0.f;
                }
                ushort hh[8], ll[8];
#pragma unroll
                for (int j = 0; j < 8; ++j) {
                    hh[j] = f2bf(v[j]);
                    ll[j] = f2bf(v[j] - bf2f(hh[j]));
                }
                int off = ar * 32 + ((slot ^ ((ar >> 1) & 3)) << 3);
                *(int4*)&Ah[off] = *(int4*)hh;
                *(int4*)&Al[off] = *(int4*)ll;
            }
        }
        {
            size_t base = (size_t)(col0 + br) * ldb + k0 + bs * 8;
            int4 vh = *(const int4*)&BTh[base];
            int4 vl = *(const int4*)&BTl[base];
            int off = br * 32 + ((bs ^ ((br >> 1) & 3)) << 3);
            *(int4*)&Bh[off] = vh;
            *(int4*)&Bl[off] = vl;
        }
        __syncthreads();
        bf16x8 afh[4], afl[4], bfh[2], bfl[2];
#pragma unroll
        for (int m = 0; m < 4; ++m) {
            int r = wr * 64 + m * 16 + fr;
            int off = r * 32 + ((fs ^ ((r >> 1) & 3)) << 3);
            afh[m] = *(const bf16x8*)&Ah[off];
            afl[m] = *(const bf16x8*)&Al[off];
        }
#pragma unroll
        for (int n = 0; n < 2; ++n) {
            int r = wc * 32 + n * 16 + fr;
            int off = r * 32 + ((fs ^ ((r >> 1) & 3)) << 3);
            bfh[n] = *(const bf16x8*)&Bh[off];
            bfl[n] = *(const bf16x8*)&Bl[off];
        }
#pragma unroll
        for (int m = 0; m < 4; ++m)
#pragma unroll
            for (int n = 0; n < 2; ++n) {
                acc[m][n] = __builtin_amdgcn_mfma_f32_16x16x32_bf16(afh[m], bfh[n], acc[m][n], 0, 0, 0);
                acc[m][n] = __builtin_amdgcn_mfma_f32_16x16x32_bf16(afh[m], bfl[n], acc[m][n], 0, 0, 0);
                acc[m][n] = __builtin_amdgcn_mfma_f32_16x16x32_bf16(afl[m], bfh[n], acc[m][n], 0, 0, 0);
            }
        __syncthreads();
    }
    float* Cp = Cpart + (size_t)blockIdx.z * NN * Ncols;
#pragma unroll
    for (int m = 0; m < 4; ++m)
#pragma unroll
        for (int n = 0; n < 2; ++n)
#pragma unroll
            for (int r = 0; r < 4; ++r) {
                int row = row0 + wr * 64 + m * 16 + fs * 4 + r;
                int col = col0 + wc * 32 + n * 16 + fr;
                Cp[(size_t)row * Ncols + col] = acc[m][n][r];
            }
}

// ---------------------------------------------------------------------------
__global__ __launch_bounds__(256) void conv_w1t_kernel(
    const float* __restrict__ W1, ushort* __restrict__ Wh, ushort* __restrict__ Wl)
{
    __shared__ float t[64][65];
    const int tid = threadIdx.x;
    const int k0 = blockIdx.x * 64, n0 = blockIdx.y * 64;
    const int kk = tid >> 2, c4 = (tid & 3) * 16;
#pragma unroll
    for (int j = 0; j < 4; ++j) {
        int k = k0 + kk;
        float4 v = make_float4(0.f, 0.f, 0.f, 0.f);
        if (k < NFEAT) v = *(const float4*)&W1[(size_t)k * HID + n0 + c4 + j * 4];
        t[kk][c4 + j * 4 + 0] = v.x; t[kk][c4 + j * 4 + 1] = v.y;
        t[kk][c4 + j * 4 + 2] = v.z; t[kk][c4 + j * 4 + 3] = v.w;
    }
    __syncthreads();
    const int on = tid >> 2, ok4 = (tid & 3) * 16;
#pragma unroll
    for (int j = 0; j < 4; ++j) {
        ushort hh[4], ll[4];
#pragma unroll
        for (int i = 0; i < 4; ++i) {
            float v = t[ok4 + j * 4 + i][on];
            hh[i] = f2bf(v); ll[i] = f2bf(v - bf2f(hh[i]));
        }
        size_t o = (size_t)(n0 + on) * KPAD + k0 + ok4 + j * 4;
        *(ushort4*)&Wh[o] = *(ushort4*)hh;
        *(ushort4*)&Wl[o] = *(ushort4*)ll;
    }
}

// ---------------------------------------------------------------------------
__global__ __launch_bounds__(256) void reduce_h1_kernel(
    const float* __restrict__ part, float* __restrict__ h1,
    ushort* __restrict__ Th, ushort* __restrict__ Tl)
{
    __shared__ float t[64][65];
    const int tid = threadIdx.x;
    const int r0 = blockIdx.x * 64, c0 = blockIdx.y * 64;
    const int tr = tid >> 2, tc4 = (tid & 3) * 16;
#pragma unroll
    for (int j = 0; j < 4; ++j) {
        size_t o = (size_t)(r0 + tr) * HID + c0 + tc4 + j * 4;
        float4 s = *(const float4*)&part[o];
#pragma unroll
        for (int ch = 1; ch < 4; ++ch) {
            float4 p = *(const float4*)&part[(size_t)ch * NN * HID + o];
            s.x += p.x; s.y += p.y; s.z += p.z; s.w += p.w;
        }
        *(float4*)&h1[o] = s;
        t[tr][tc4 + j * 4 + 0] = s.x; t[tr][tc4 + j * 4 + 1] = s.y;
        t[tr][tc4 + j * 4 + 2] = s.z; t[tr][tc4 + j * 4 + 3] = s.w;
    }
    __syncthreads();
    const int oc = tid >> 2, ok4 = (tid & 3) * 16;
#pragma unroll
    for (int j = 0; j < 4; ++j) {
        ushort hh[4], ll[4];
#pragma unroll
        for (int i = 0; i < 4; ++i) {
            float v = t[ok4 + j * 4 + i][oc];
            hh[i] = f2bf(v); ll[i] = f2bf(v - bf2f(hh[i]));
        }
        size_t o = (size_t)(c0 + oc) * NN + r0 + ok4 + j * 4;
        *(ushort4*)&Th[o] = *(ushort4*)hh;
        *(ushort4*)&Tl[o] = *(ushort4*)ll;
    }
}

// ---------------------------------------------------------------------------
__global__ __launch_bounds__(256) void reduce_g1_kernel(
    const float* __restrict__ part, float* __restrict__ g1)
{
    const int tid = threadIdx.x;
    const int r0 = blockIdx.x * 64, c0 = blockIdx.y * 64;
    const int tr = tid >> 2, tc4 = (tid & 3) * 16;
#pragma unroll
    for (int j = 0; j < 4; ++j) {
        size_t o = (size_t)(r0 + tr) * HID + c0 + tc4 + j * 4;
        float4 s = *(const float4*)&part[o];
#pragma unroll
        for (int ch = 1; ch < 4; ++ch) {
            float4 p = *(const float4*)&part[(size_t)ch * NN * HID + o];
            s.x += p.x; s.y += p.y; s.z += p.z; s.w += p.w;
        }
        s.x = (s.x > 0.f) ? s.x : expm1f(s.x);
        s.y = (s.y > 0.f) ? s.y : expm1f(s.y);
        s.z = (s.z > 0.f) ? s.z : expm1f(s.z);
        s.w = (s.w > 0.f) ? s.w : expm1f(s.w);
        *(float4*)&g1[o] = s;
    }
}

// ---------------------------------------------------------------------------
__global__ __launch_bounds__(256) void fvec_kernel(
    const float* __restrict__ h, int D,
    const float* __restrict__ a_s, const float* __restrict__ a_n,
    float* __restrict__ fs, float* __restrict__ fn, int nrows)
{
    const int wv = threadIdx.x >> 6;
    const int lane = threadIdx.x & 63;
    const int row = blockIdx.x * 4 + wv;
    if (row >= nrows) return;
    float s = 0.f, n = 0.f;
    for (int d = lane; d < D; d += 64) {
        float v = h[(size_t)row * D + d];
        s += v * a_s[d];
        n += v * a_n[d];
    }
#pragma unroll
    for (int off = 32; off > 0; off >>= 1) {
        s += __shfl_down(s, off, 64);
        n += __shfl_down(n, off, 64);
    }
    if (lane == 0) { fs[row] = s; fn[row] = n; }
}

// ---------------------------------------------------------------------------
// Layer-1 softmax row: writes bf16 hi/lo planes for the MFMA gemm.
// ---------------------------------------------------------------------------
__global__ __launch_bounds__(256) void att_row_kernel(
    const float* __restrict__ Mmat, const float* __restrict__ adj,
    const float* __restrict__ fs, const float* __restrict__ fn,
    ushort* __restrict__ att_hi, ushort* __restrict__ att_lo)
{
    __shared__ float e_s[NN];
    __shared__ float wred[4];
    __shared__ float wsum[4];
    const int row = blockIdx.x;
    const int tid = threadIdx.x;
    const int lane = tid & 63, wv = tid >> 6;
    const float fsi = fs[row];

    float lmax = -3.0e38f;
#pragma unroll
    for (int t = 0; t < 4; ++t) {
        int j = (t * 256 + tid) * 4;
        float4 m4 = *(const float4*)&Mmat[(size_t)row * NN + j];
        float4 a4 = *(const float4*)&adj[(size_t)row * NN + j];
        float4 f4 = *(const float4*)&fn[j];
        float e[4];
        e[0] = (fsi + f4.x) * m4.x; e[1] = (fsi + f4.y) * m4.y;
        e[2] = (fsi + f4.z) * m4.z; e[3] = (fsi + f4.w) * m4.w;
        float a[4] = {a4.x, a4.y, a4.z, a4.w};
#pragma unroll
        for (int i = 0; i < 4; ++i) {
            float v = e[i];
            v = (v > 0.f) ? v : 0.2f * v;
            v = (a[i] > 0.f) ? v : -9e15f;
            e_s[j + i] = v;
            lmax = fmaxf(lmax, v);
        }
    }
#pragma unroll
    for (int off = 32; off > 0; off >>= 1)
        lmax = fmaxf(lmax, __shfl_down(lmax, off, 64));
    if (lane == 0) wred[wv] = lmax;
    __syncthreads();
    const float m = fmaxf(fmaxf(wred[0], wred[1]), fmaxf(wred[2], wred[3]));

    float lsum = 0.f;
#pragma unroll
    for (int t = 0; t < 16; ++t) {
        int j = t * 256 + tid;
        float p = expf(e_s[j] - m);
        e_s[j] = p;
        lsum += p;
    }
#pragma unroll
    for (int off = 32; off > 0; off >>= 1)
        lsum += __shfl_down(lsum, off, 64);
    if (lane == 0) wsum[wv] = lsum;
    __syncthreads();
    const float inv = 1.f / (wsum[0] + wsum[1] + wsum[2] + wsum[3]);
#pragma unroll
    for (int t = 0; t < 16; ++t) {
        int j = t * 256 + tid;
        float p = e_s[j] * inv;
        ushort h = f2bf(p);
        att_hi[(size_t)row * NN + j] = h;
        att_lo[(size_t)row * NN + j] = f2bf(p - bf2f(h));
    }
}

// ---------------------------------------------------------------------------
// Layer-2 fused softmax + PV: g2[row,:] = elu( softmax_row @ h2 ).
// One block per row. h2 stays L2-resident (256 KB).
// ---------------------------------------------------------------------------
__global__ __launch_bounds__(256) void att_pv_kernel(
    const float* __restrict__ Mmat, const float* __restrict__ adj,
    const float* __restrict__ fs, const float* __restrict__ fn,
    const float* __restrict__ h2, float* __restrict__ g2)
{
    __shared__ float e_s[NN];
    __shared__ float wred[4];
    __shared__ float red[4][16];
    const int row = blockIdx.x;
    const int tid = threadIdx.x;
    const int lane = tid & 63, wv = tid >> 6;
    const float fsi = fs[row];

    float lmax = -3.0e38f;
#pragma unroll
    for (int t = 0; t < 4; ++t) {
        int j = (t * 256 + tid) * 4;
        float4 m4 = *(const float4*)&Mmat[(size_t)row * NN + j];
        float4 a4 = *(const float4*)&adj[(size_t)row * NN + j];
        float4 f4 = *(const float4*)&fn[j];
        float e[4];
        e[0] = (fsi + f4.x) * m4.x; e[1] = (fsi + f4.y) * m4.y;
        e[2] = (fsi + f4.z) * m4.z; e[3] = (fsi + f4.w) * m4.w;
        float a[4] = {a4.x, a4.y, a4.z, a4.w};
#pragma unroll
        for (int i = 0; i < 4; ++i) {
            float v = e[i];
            v = (v > 0.f) ? v : 0.2f * v;
            v = (a[i] > 0.f) ? v : -9e15f;
            e_s[j + i] = v;
            lmax = fmaxf(lmax, v);
        }
    }
#pragma unroll
    for (int off = 32; off > 0; off >>= 1)
        lmax = fmaxf(lmax, __shfl_down(lmax, off, 64));
    if (lane == 0) wred[wv] = lmax;
    __syncthreads();
    const float m = fmaxf(fmaxf(wred[0], wred[1]), fmaxf(wred[2], wred[3]));

    // fused sum + PV accumulate (unnormalized)
    float lsum = 0.f;
    float acc[16] = {};
#pragma unroll 4
    for (int t = 0; t < 16; ++t) {
        int j = t * 256 + tid;
        float p = expf(e_s[j] - m);
        lsum += p;
        const float4* hv = (const float4*)&h2[(size_t)j * EMB];
        float4 h0 = hv[0], h1v = hv[1], h2v = hv[2], h3 = hv[3];
        acc[0]  += p * h0.x;  acc[1]  += p * h0.y;
        acc[2]  += p * h0.z;  acc[3]  += p * h0.w;
        acc[4]  += p * h1v.x; acc[5]  += p * h1v.y;
        acc[6]  += p * h1v.z; acc[7]  += p * h1v.w;
        acc[8]  += p * h2v.x; acc[9]  += p * h2v.y;
        acc[10] += p * h2v.z; acc[11] += p * h2v.w;
        acc[12] += p * h3.x;  acc[13] += p * h3.y;
        acc[14] += p * h3.z;  acc[15] += p * h3.w;
    }
#pragma unroll
    for (int off = 32; off > 0; off >>= 1) {
        lsum += __shfl_down(lsum, off, 64);
#pragma unroll
        for (int d = 0; d < 16; ++d)
            acc[d] += __shfl_down(acc[d], off, 64);
    }
    if (lane == 0) {
        wred[wv] = lsum;
#pragma unroll
        for (int d = 0; d < 16; ++d) red[wv][d] = acc[d];
    }
    __syncthreads();
    if (tid < 16) {
        const float tot = wred[0] + wred[1] + wred[2] + wred[3];
        const float inv = 1.f / tot;
        float v = (red[0][tid] + red[1][tid] + red[2][tid] + red[3][tid]) * inv;
        v = (v > 0.f) ? v : expm1f(v);
        g2[(size_t)row * EMB + tid] = v;
    }
}

// ---------------------------------------------------------------------------
__global__ __launch_bounds__(256) void gemm_h2_kernel(
    const float* __restrict__ g1, const float* __restrict__ W2,
    float* __restrict__ h2)
{
    __shared__ float Ws[256][16];
    __shared__ float Gs[16][257];
    const int tid = threadIdx.x;
    const int row0 = blockIdx.x * 16;
#pragma unroll
    for (int i = 0; i < 16; ++i) {
        int idx = tid + i * 256;
        Ws[idx >> 4][idx & 15] = W2[idx];
    }
#pragma unroll
    for (int i = 0; i < 16; ++i) {
        int idx = tid + i * 256;
        Gs[idx >> 8][idx & 255] = g1[(size_t)(row0 + (idx >> 8)) * HID + (idx & 255)];
    }
    __syncthreads();
    const int r = tid >> 4, c = tid & 15;
    float acc = 0.f;
#pragma unroll 8
    for (int k = 0; k < 256; ++k)
        acc += Gs[r][k] * Ws[k][c];
    h2[(size_t)(row0 + r) * EMB + c] = acc;
}

// ---------------------------------------------------------------------------
__global__ __launch_bounds__(256) void normalize_kernel(
    const float* __restrict__ g2, float* __restrict__ z)
{
    const int row = blockIdx.x * 256 + threadIdx.x;
    const float4* src = reinterpret_cast<const float4*>(&g2[(size_t)row * EMB]);
    float4 v[4];
    float ss = 0.f;
#pragma unroll
    for (int i = 0; i < 4; ++i) {
        v[i] = src[i];
        ss += v[i].x * v[i].x + v[i].y * v[i].y + v[i].z * v[i].z + v[i].w * v[i].w;
    }
    const float inv = 1.f / fmaxf(sqrtf(ss), 1e-12f);
    float4* dst = reinterpret_cast<float4*>(&z[(size_t)row * EMB]);
#pragma unroll
    for (int i = 0; i < 4; ++i) {
        float4 o; o.x = v[i].x * inv; o.y = v[i].y * inv;
        o.z = v[i].z * inv; o.w = v[i].w * inv;
        dst[i] = o;
    }
}

// ---------------------------------------------------------------------------
__global__ __launch_bounds__(256) void apred_kernel(
    const float* __restrict__ z, float* __restrict__ out)
{
    __shared__ float zr[64][20];
    __shared__ float zc[64][20];
    const int tid = threadIdx.x;
    const int r0 = blockIdx.y * 64, c0 = blockIdx.x * 64;
#pragma unroll
    for (int i = 0; i < 4; ++i) {
        int idx = tid + i * 256;
        int rr = idx >> 4, d = idx & 15;
        zr[rr][d] = z[(size_t)(r0 + rr) * EMB + d];
        zc[rr][d] = z[(size_t)(c0 + rr) * EMB + d];
    }
    __syncthreads();
    const int tx = tid & 15, ty = tid >> 4;
    float rb[4][16], cb[4][16];
#pragma unroll
    for (int i = 0; i < 4; ++i)
#pragma unroll
        for (int d = 0; d < 16; ++d) {
            rb[i][d] = zr[ty * 4 + i][d];
            cb[i][d] = zc[tx * 4 + i][d];
        }
#pragma unroll
    for (int i = 0; i < 4; ++i) {
        float4 o;
        float v[4];
#pragma unroll
        for (int j = 0; j < 4; ++j) {
            float s = 0.f;
#pragma unroll
            for (int d = 0; d < 16; ++d) s += rb[i][d] * cb[j][d];
            v[j] = 1.f / (1.f + expf(-s));
        }
        o.x = v[0]; o.y = v[1]; o.z = v[2]; o.w = v[3];
        *reinterpret_cast<float4*>(
            &out[(size_t)(r0 + ty * 4 + i) * NN + c0 + tx * 4]) = o;
    }
}

// ---------------------------------------------------------------------------
extern "C" void kernel_launch(void* const* d_in, const int* in_sizes, int n_in,
                              void* d_out, int out_size, void* d_ws, size_t ws_size,
                              hipStream_t stream)
{
    const float* x    = (const float*)d_in[0];
    const float* adj  = (const float*)d_in[1];
    const float* Mm   = (const float*)d_in[2];
    const float* W1   = (const float*)d_in[3];
    const float* a_s1 = (const float*)d_in[4];
    const float* a_n1 = (const float*)d_in[5];
    const float* W2   = (const float*)d_in[6];
    const float* a_s2 = (const float*)d_in[7];
    const float* a_n2 = (const float*)d_in[8];

    float* out = (float*)d_out;
    // layer-1 att bf16 planes live in the A_pred region (exactly NN*NN*4 bytes)
    ushort* att_hi = (ushort*)d_out;
    ushort* att_lo = att_hi + (size_t)NN * NN;
    float*  z      = out + (size_t)NN * NN;

    char* w = (char*)d_ws;
    float* part  = (float*)w;  w += (size_t)4 * NN * HID * 4;   // 16.8 MB
    float* h1    = (float*)w;  w += (size_t)NN * HID * 4;
    float* g1    = (float*)w;  w += (size_t)NN * HID * 4;
    ushort* h1Th = (ushort*)w; w += (size_t)HID * NN * 2;
    ushort* h1Tl = (ushort*)w; w += (size_t)HID * NN * 2;
    ushort* W1Th = (ushort*)w; w += (size_t)HID * KPAD * 2;
    ushort* W1Tl = (ushort*)w; w += (size_t)HID * KPAD * 2;
    float* h2    = (float*)w;  w += (size_t)NN * EMB * 4;
    float* g2    = (float*)w;  w += (size_t)NN * EMB * 4;
    float* fs1   = (float*)w;  w += NN * 4;
    float* fn1   = (float*)w;  w += NN * 4;
    float* fs2   = (float*)w;  w += NN * 4;
    float* fn2   = (float*)w;  w += NN * 4;

    // ---- layer 1 ----
    conv_w1t_kernel<<<dim3(30, 4), 256, 0, stream>>>(W1, W1Th, W1Tl);
    gemm_bf16x2<0><<<dim3(32, 4, 4), 256, 0, stream>>>(
        x, nullptr, W1Th, W1Tl, KPAD, NFEAT, NFEAT, 480, part, HID);
    reduce_h1_kernel<<<dim3(64, 4), 256, 0, stream>>>(part, h1, h1Th, h1Tl);
    fvec_kernel<<<1024, 256, 0, stream>>>(h1, HID, a_s1, a_n1, fs1, fn1, NN);
    att_row_kernel<<<NN, 256, 0, stream>>>(Mm, adj, fs1, fn1, att_hi, att_lo);
    gemm_bf16x2<1><<<dim3(32, 4, 4), 256, 0, stream>>>(
        att_hi, att_lo, h1Th, h1Tl, NN, NN, NN, 1024, part, HID);
    reduce_g1_kernel<<<dim3(64, 4), 256, 0, stream>>>(part, g1);

    // ---- layer 2 ----
    gemm_h2_kernel<<<256, 256, 0, stream>>>(g1, W2, h2);
    fvec_kernel<<<1024, 256, 0, stream>>>(h2, EMB, a_s2, a_n2, fs2, fn2, NN);
    att_pv_kernel<<<NN, 256, 0, stream>>>(Mm, adj, fs2, fn2, h2, g2);

    // ---- epilogue ----
    normalize_kernel<<<16, 256, 0, stream>>>(g2, z);
    apred_kernel<<<dim3(64, 64), 256, 0, stream>>>(z, out);
}

// Round 4
// 114.041 us; speedup vs baseline: 10.1578x; 2.1007x over previous
//
#include <hip/hip_runtime.h>
#include <math.h>

#define NN 4096
#define NFEAT 1870
#define KPAD 1920
#define HID 256
#define EMB 16
#define MAXDEG 128

typedef __attribute__((ext_vector_type(8))) short bf16x8;
typedef __attribute__((ext_vector_type(4))) float f32x4;

__device__ __forceinline__ ushort f2bf(float f) {
    unsigned u = __builtin_bit_cast(unsigned, f);
    u += 0x7fffu + ((u >> 16) & 1u);
    return (ushort)(u >> 16);
}
__device__ __forceinline__ float bf2f(ushort h) {
    unsigned u = ((unsigned)h) << 16;
    return __builtin_bit_cast(float, u);
}

// ---------------------------------------------------------------------------
// h1 partials = x[., kchunk] @ W1 via bf16x2 split-precision MFMA.
// Tile 128x64, 4 waves (2x2), BK=32, split-K over blockIdx.z.
// A = fp32 x with on-the-fly hi/lo split; B = bf16 hi/lo planes, transposed.
// ---------------------------------------------------------------------------
__global__ __launch_bounds__(256) void gemm_xw1(
    const float* __restrict__ Af,
    const ushort* __restrict__ BTh, const ushort* __restrict__ BTl, int ldb,
    int lda, int Kreal, int CHUNK,
    float* __restrict__ Cpart, int Ncols)
{
    __shared__ ushort Ah[128 * 32];
    __shared__ ushort Al[128 * 32];
    __shared__ ushort Bh[64 * 32];
    __shared__ ushort Bl[64 * 32];

    const int tid = threadIdx.x;
    const int lane = tid & 63;
    const int w = tid >> 6;
    const int wr = w >> 1, wc = w & 1;
    const int row0 = blockIdx.x * 128;
    const int col0 = blockIdx.y * 64;
    const int kbeg = blockIdx.z * CHUNK;
    const int kend = min(Kreal, kbeg + CHUNK);
    const int nsteps = (kend - kbeg + 31) >> 5;

    const int ar = tid >> 1;
    const int as2 = (tid & 1) * 2;
    const int br = tid >> 2;
    const int bs = tid & 3;

    const int fr = lane & 15;
    const int fs = lane >> 4;

    f32x4 acc[4][2] = {};

    for (int ks = 0; ks < nsteps; ++ks) {
        const int k0 = kbeg + (ks << 5);
        {
            size_t base = (size_t)(row0 + ar) * lda;
#pragma unroll
            for (int c = 0; c < 2; ++c) {
                int slot = as2 + c;
                int kk = k0 + slot * 8;
                float v[8];
                if (kk + 8 <= Kreal) {
#pragma unroll
                    for (int j = 0; j < 4; ++j) {
                        float2 t2 = *(const float2*)&Af[base + kk + j * 2];
                        v[j * 2] = t2.x; v[j * 2 + 1] = t2.y;
                    }
                } else {
#pragma unroll
                    for (int j = 0; j < 8; ++j)
                        v[j] = (kk + j < Kreal) ? Af[base + kk + j] : 0.f;
                }
                ushort hh[8], ll[8];
#pragma unroll
                for (int j = 0; j < 8; ++j) {
                    hh[j] = f2bf(v[j]);
                    ll[j] = f2bf(v[j] - bf2f(hh[j]));
                }
                int off = ar * 32 + ((slot ^ ((ar >> 1) & 3)) << 3);
                *(int4*)&Ah[off] = *(int4*)hh;
                *(int4*)&Al[off] = *(int4*)ll;
            }
        }
        {
            size_t base = (size_t)(col0 + br) * ldb + k0 + bs * 8;
            int4 vh = *(const int4*)&BTh[base];
            int4 vl = *(const int4*)&BTl[base];
            int off = br * 32 + ((bs ^ ((br >> 1) & 3)) << 3);
            *(int4*)&Bh[off] = vh;
            *(int4*)&Bl[off] = vl;
        }
        __syncthreads();
        bf16x8 afh[4], afl[4], bfh[2], bfl[2];
#pragma unroll
        for (int m = 0; m < 4; ++m) {
            int r = wr * 64 + m * 16 + fr;
            int off = r * 32 + ((fs ^ ((r >> 1) & 3)) << 3);
            afh[m] = *(const bf16x8*)&Ah[off];
            afl[m] = *(const bf16x8*)&Al[off];
        }
#pragma unroll
        for (int n = 0; n < 2; ++n) {
            int r = wc * 32 + n * 16 + fr;
            int off = r * 32 + ((fs ^ ((r >> 1) & 3)) << 3);
            bfh[n] = *(const bf16x8*)&Bh[off];
            bfl[n] = *(const bf16x8*)&Bl[off];
        }
#pragma unroll
        for (int m = 0; m < 4; ++m)
#pragma unroll
            for (int n = 0; n < 2; ++n) {
                acc[m][n] = __builtin_amdgcn_mfma_f32_16x16x32_bf16(afh[m], bfh[n], acc[m][n], 0, 0, 0);
                acc[m][n] = __builtin_amdgcn_mfma_f32_16x16x32_bf16(afh[m], bfl[n], acc[m][n], 0, 0, 0);
                acc[m][n] = __builtin_amdgcn_mfma_f32_16x16x32_bf16(afl[m], bfh[n], acc[m][n], 0, 0, 0);
            }
        __syncthreads();
    }
    float* Cp = Cpart + (size_t)blockIdx.z * NN * Ncols;
#pragma unroll
    for (int m = 0; m < 4; ++m)
#pragma unroll
        for (int n = 0; n < 2; ++n)
#pragma unroll
            for (int r = 0; r < 4; ++r) {
                int row = row0 + wr * 64 + m * 16 + fs * 4 + r;
                int col = col0 + wc * 32 + n * 16 + fr;
                Cp[(size_t)row * Ncols + col] = acc[m][n][r];
            }
}

// ---------------------------------------------------------------------------
// W1 [NFEAT][HID] fp32 -> W1T hi/lo planes [HID][KPAD] bf16, zero-padded K.
// ---------------------------------------------------------------------------
__global__ __launch_bounds__(256) void conv_w1t_kernel(
    const float* __restrict__ W1, ushort* __restrict__ Wh, ushort* __restrict__ Wl)
{
    __shared__ float t[64][65];
    const int tid = threadIdx.x;
    const int k0 = blockIdx.x * 64, n0 = blockIdx.y * 64;
    const int kk = tid >> 2, c4 = (tid & 3) * 16;
#pragma unroll
    for (int j = 0; j < 4; ++j) {
        int k = k0 + kk;
        float4 v = make_float4(0.f, 0.f, 0.f, 0.f);
        if (k < NFEAT) v = *(const float4*)&W1[(size_t)k * HID + n0 + c4 + j * 4];
        t[kk][c4 + j * 4 + 0] = v.x; t[kk][c4 + j * 4 + 1] = v.y;
        t[kk][c4 + j * 4 + 2] = v.z; t[kk][c4 + j * 4 + 3] = v.w;
    }
    __syncthreads();
    const int on = tid >> 2, ok4 = (tid & 3) * 16;
#pragma unroll
    for (int j = 0; j < 4; ++j) {
        ushort hh[4], ll[4];
#pragma unroll
        for (int i = 0; i < 4; ++i) {
            float v = t[ok4 + j * 4 + i][on];
            hh[i] = f2bf(v); ll[i] = f2bf(v - bf2f(hh[i]));
        }
        size_t o = (size_t)(n0 + on) * KPAD + k0 + ok4 + j * 4;
        *(ushort4*)&Wh[o] = *(ushort4*)hh;
        *(ushort4*)&Wl[o] = *(ushort4*)ll;
    }
}

// ---------------------------------------------------------------------------
// h1 = sum of 4 split-K partials (plain f32).
// ---------------------------------------------------------------------------
__global__ __launch_bounds__(256) void reduce_h1_kernel(
    const float* __restrict__ part, float* __restrict__ h1)
{
    const size_t i = ((size_t)blockIdx.x * 256 + threadIdx.x) * 4;
    float4 s = *(const float4*)&part[i];
#pragma unroll
    for (int ch = 1; ch < 4; ++ch) {
        float4 p = *(const float4*)&part[(size_t)ch * NN * HID + i];
        s.x += p.x; s.y += p.y; s.z += p.z; s.w += p.w;
    }
    *(float4*)&h1[i] = s;
}

// ---------------------------------------------------------------------------
// Sparse extraction: per row, ordered list of neighbor indices (wave ballot
// compaction — deterministic) + gathered M values. One wave per row.
// ---------------------------------------------------------------------------
__global__ __launch_bounds__(256) void extract_kernel(
    const float* __restrict__ adj, const float* __restrict__ Mmat,
    int* __restrict__ nnz, int* __restrict__ gidx, float* __restrict__ Mg)
{
    __shared__ int sidx[4][MAXDEG];
    const int tid = threadIdx.x;
    const int wv = tid >> 6, lane = tid & 63;
    const int row = blockIdx.x * 4 + wv;

    int base = 0;
#pragma unroll 4
    for (int t = 0; t < 16; ++t) {
        int j0 = t * 256 + lane * 4;
        float4 a = *(const float4*)&adj[(size_t)row * NN + j0];
        float av[4] = {a.x, a.y, a.z, a.w};
#pragma unroll
        for (int c = 0; c < 4; ++c) {
            unsigned long long mb = __ballot(av[c] > 0.f);
            if (av[c] > 0.f) {
                int pos = base + (int)__popcll(mb & ((1ull << lane) - 1ull));
                if (pos < MAXDEG) sidx[wv][pos] = j0 + c;
            }
            base += (int)__popcll(mb);
        }
    }
    const int cnt = min(base, MAXDEG);
    if (lane == 0) nnz[row] = cnt;
    // gather M at neighbor positions, store compact idx + Mg
    for (int s = lane; s < cnt; s += 64) {
        int j = sidx[wv][s];
        gidx[(size_t)row * MAXDEG + s] = j;
        Mg[(size_t)row * MAXDEG + s] = Mmat[(size_t)row * NN + j];
    }
}

// ---------------------------------------------------------------------------
// fs[i] = h[i,:].a_self ; fn[i] = h[i,:].a_neigh.  One wave per row.
// ---------------------------------------------------------------------------
__global__ __launch_bounds__(256) void fvec_kernel(
    const float* __restrict__ h, int D,
    const float* __restrict__ a_s, const float* __restrict__ a_n,
    float* __restrict__ fs, float* __restrict__ fn, int nrows)
{
    const int wv = threadIdx.x >> 6;
    const int lane = threadIdx.x & 63;
    const int row = blockIdx.x * 4 + wv;
    if (row >= nrows) return;
    float s = 0.f, n = 0.f;
    for (int d = lane; d < D; d += 64) {
        float v = h[(size_t)row * D + d];
        s += v * a_s[d];
        n += v * a_n[d];
    }
#pragma unroll
    for (int off = 32; off > 0; off >>= 1) {
        s += __shfl_down(s, off, 64);
        n += __shfl_down(n, off, 64);
    }
    if (lane == 0) { fs[row] = s; fn[row] = n; }
}

// ---------------------------------------------------------------------------
// Layer-1 fused sparse softmax + SpMM: g1[row,:] = elu( softmax_nb @ h1 ).
// One block (256 thr) per row; thread = output dim.
// ---------------------------------------------------------------------------
__global__ __launch_bounds__(256) void spmm1_kernel(
    const int* __restrict__ nnz, const int* __restrict__ gidx,
    const float* __restrict__ Mg,
    const float* __restrict__ fs, const float* __restrict__ fn,
    const float* __restrict__ h1, float* __restrict__ g1)
{
    __shared__ float p_s[MAXDEG];
    __shared__ int j_s[MAXDEG];
    __shared__ float wred[4], wsum[4];
    const int row = blockIdx.x;
    const int tid = threadIdx.x;
    const int lane = tid & 63, wv = tid >> 6;
    const int cnt = nnz[row];
    const float fsi = fs[row];

    float lmax = -3.0e38f;
    for (int s = tid; s < cnt; s += 256) {
        int j = gidx[(size_t)row * MAXDEG + s];
        j_s[s] = j;
        float e = (fsi + fn[j]) * Mg[(size_t)row * MAXDEG + s];
        e = (e > 0.f) ? e : 0.2f * e;
        p_s[s] = e;
        lmax = fmaxf(lmax, e);
    }
#pragma unroll
    for (int off = 32; off > 0; off >>= 1)
        lmax = fmaxf(lmax, __shfl_down(lmax, off, 64));
    if (lane == 0) wred[wv] = lmax;
    __syncthreads();
    const float m = fmaxf(fmaxf(wred[0], wred[1]), fmaxf(wred[2], wred[3]));

    float lsum = 0.f;
    for (int s = tid; s < cnt; s += 256) {
        float p = expf(p_s[s] - m);
        p_s[s] = p;
        lsum += p;
    }
#pragma unroll
    for (int off = 32; off > 0; off >>= 1)
        lsum += __shfl_down(lsum, off, 64);
    if (lane == 0) wsum[wv] = lsum;
    __syncthreads();
    const float inv = 1.f / (wsum[0] + wsum[1] + wsum[2] + wsum[3]);

    float acc = 0.f;
#pragma unroll 4
    for (int s = 0; s < cnt; ++s)
        acc += p_s[s] * h1[(size_t)j_s[s] * HID + tid];
    float v = acc * inv;
    v = (v > 0.f) ? v : expm1f(v);
    g1[(size_t)row * HID + tid] = v;
}

// ---------------------------------------------------------------------------
// Layer-2 fused sparse softmax + PV + ELU + L2-normalize -> z.
// One wave per row (4 rows / 256-thr block).
// ---------------------------------------------------------------------------
__global__ __launch_bounds__(256) void spmm2_kernel(
    const int* __restrict__ nnz, const int* __restrict__ gidx,
    const float* __restrict__ Mg,
    const float* __restrict__ fs, const float* __restrict__ fn,
    const float* __restrict__ h2, float* __restrict__ z)
{
    __shared__ float p_s[4][MAXDEG];
    __shared__ int j_s[4][MAXDEG];
    const int tid = threadIdx.x;
    const int wv = tid >> 6, lane = tid & 63;
    const int row = blockIdx.x * 4 + wv;
    const int cnt = nnz[row];
    const float fsi = fs[row];

    float lmax = -3.0e38f;
    for (int s = lane; s < cnt; s += 64) {
        int j = gidx[(size_t)row * MAXDEG + s];
        j_s[wv][s] = j;
        float e = (fsi + fn[j]) * Mg[(size_t)row * MAXDEG + s];
        e = (e > 0.f) ? e : 0.2f * e;
        p_s[wv][s] = e;
        lmax = fmaxf(lmax, e);
    }
#pragma unroll
    for (int off = 1; off < 64; off <<= 1)
        lmax = fmaxf(lmax, __shfl_xor(lmax, off, 64));

    float lsum = 0.f;
    for (int s = lane; s < cnt; s += 64) {
        float p = expf(p_s[wv][s] - lmax);
        p_s[wv][s] = p;
        lsum += p;
    }
#pragma unroll
    for (int off = 1; off < 64; off <<= 1)
        lsum += __shfl_xor(lsum, off, 64);
    const float inv = 1.f / lsum;

    const int s0 = lane >> 4, d = lane & 15;
    float acc = 0.f;
    for (int s = s0; s < cnt; s += 4)
        acc += p_s[wv][s] * h2[(size_t)j_s[wv][s] * EMB + d];
    acc += __shfl_xor(acc, 16, 64);
    acc += __shfl_xor(acc, 32, 64);

    float v = acc * inv;
    v = (v > 0.f) ? v : expm1f(v);
    // L2 normalize across the 16 dims (lanes 0..15 hold d=0..15; groups identical)
    float ss = v * v;
#pragma unroll
    for (int off = 1; off < 16; off <<= 1)
        ss += __shfl_xor(ss, off, 64);
    float zn = v / fmaxf(sqrtf(ss), 1e-12f);
    if (lane < 16) z[(size_t)row * EMB + lane] = zn;
}

// ---------------------------------------------------------------------------
// h2 = g1(NNxHID) @ W2(HIDxEMB)
// ---------------------------------------------------------------------------
__global__ __launch_bounds__(256) void gemm_h2_kernel(
    const float* __restrict__ g1, const float* __restrict__ W2,
    float* __restrict__ h2)
{
    __shared__ float Ws[256][16];
    __shared__ float Gs[16][257];
    const int tid = threadIdx.x;
    const int row0 = blockIdx.x * 16;
#pragma unroll
    for (int i = 0; i < 16; ++i) {
        int idx = tid + i * 256;
        Ws[idx >> 4][idx & 15] = W2[idx];
    }
#pragma unroll
    for (int i = 0; i < 16; ++i) {
        int idx = tid + i * 256;
        Gs[idx >> 8][idx & 255] = g1[(size_t)(row0 + (idx >> 8)) * HID + (idx & 255)];
    }
    __syncthreads();
    const int r = tid >> 4, c = tid & 15;
    float acc = 0.f;
#pragma unroll 8
    for (int k = 0; k < 256; ++k)
        acc += Gs[r][k] * Ws[k][c];
    h2[(size_t)(row0 + r) * EMB + c] = acc;
}

// ---------------------------------------------------------------------------
// A_pred = sigmoid(z @ z^T).  64x64 tile per block.
// ---------------------------------------------------------------------------
__global__ __launch_bounds__(256) void apred_kernel(
    const float* __restrict__ z, float* __restrict__ out)
{
    __shared__ float zr[64][20];
    __shared__ float zc[64][20];
    const int tid = threadIdx.x;
    const int r0 = blockIdx.y * 64, c0 = blockIdx.x * 64;
#pragma unroll
    for (int i = 0; i < 4; ++i) {
        int idx = tid + i * 256;
        int rr = idx >> 4, d = idx & 15;
        zr[rr][d] = z[(size_t)(r0 + rr) * EMB + d];
        zc[rr][d] = z[(size_t)(c0 + rr) * EMB + d];
    }
    __syncthreads();
    const int tx = tid & 15, ty = tid >> 4;
    float rb[4][16], cb[4][16];
#pragma unroll
    for (int i = 0; i < 4; ++i)
#pragma unroll
        for (int d = 0; d < 16; ++d) {
            rb[i][d] = zr[ty * 4 + i][d];
            cb[i][d] = zc[tx * 4 + i][d];
        }
#pragma unroll
    for (int i = 0; i < 4; ++i) {
        float4 o;
        float v[4];
#pragma unroll
        for (int j = 0; j < 4; ++j) {
            float s = 0.f;
#pragma unroll
            for (int d = 0; d < 16; ++d) s += rb[i][d] * cb[j][d];
            v[j] = 1.f / (1.f + expf(-s));
        }
        o.x = v[0]; o.y = v[1]; o.z = v[2]; o.w = v[3];
        *reinterpret_cast<float4*>(
            &out[(size_t)(r0 + ty * 4 + i) * NN + c0 + tx * 4]) = o;
    }
}

// ---------------------------------------------------------------------------
extern "C" void kernel_launch(void* const* d_in, const int* in_sizes, int n_in,
                              void* d_out, int out_size, void* d_ws, size_t ws_size,
                              hipStream_t stream)
{
    const float* x    = (const float*)d_in[0];
    const float* adj  = (const float*)d_in[1];
    const float* Mm   = (const float*)d_in[2];
    const float* W1   = (const float*)d_in[3];
    const float* a_s1 = (const float*)d_in[4];
    const float* a_n1 = (const float*)d_in[5];
    const float* W2   = (const float*)d_in[6];
    const float* a_s2 = (const float*)d_in[7];
    const float* a_n2 = (const float*)d_in[8];

    float* out = (float*)d_out;
    float* z   = out + (size_t)NN * NN;

    char* w = (char*)d_ws;
    float* part  = (float*)w;  w += (size_t)4 * NN * HID * 4;   // 16.8 MB
    float* h1    = (float*)w;  w += (size_t)NN * HID * 4;
    float* g1    = (float*)w;  w += (size_t)NN * HID * 4;
    ushort* W1Th = (ushort*)w; w += (size_t)HID * KPAD * 2;
    ushort* W1Tl = (ushort*)w; w += (size_t)HID * KPAD * 2;
    float* h2    = (float*)w;  w += (size_t)NN * EMB * 4;
    int*   nnzp  = (int*)w;    w += NN * 4;
    int*   gidx  = (int*)w;    w += (size_t)NN * MAXDEG * 4;    // 2 MB
    float* Mg    = (float*)w;  w += (size_t)NN * MAXDEG * 4;    // 2 MB
    float* fs1   = (float*)w;  w += NN * 4;
    float* fn1   = (float*)w;  w += NN * 4;
    float* fs2   = (float*)w;  w += NN * 4;
    float* fn2   = (float*)w;  w += NN * 4;

    // ---- sparsity extraction (used by both layers) ----
    extract_kernel<<<NN / 4, 256, 0, stream>>>(adj, Mm, nnzp, gidx, Mg);

    // ---- layer 1 ----
    conv_w1t_kernel<<<dim3(30, 4), 256, 0, stream>>>(W1, W1Th, W1Tl);
    gemm_xw1<<<dim3(32, 4, 4), 256, 0, stream>>>(
        x, W1Th, W1Tl, KPAD, NFEAT, NFEAT, 480, part, HID);
    reduce_h1_kernel<<<NN * HID / 1024, 256, 0, stream>>>(part, h1);
    fvec_kernel<<<1024, 256, 0, stream>>>(h1, HID, a_s1, a_n1, fs1, fn1, NN);
    spmm1_kernel<<<NN, 256, 0, stream>>>(nnzp, gidx, Mg, fs1, fn1, h1, g1);

    // ---- layer 2 ----
    gemm_h2_kernel<<<256, 256, 0, stream>>>(g1, W2, h2);
    fvec_kernel<<<1024, 256, 0, stream>>>(h2, EMB, a_s2, a_n2, fs2, fn2, NN);
    spmm2_kernel<<<NN / 4, 256, 0, stream>>>(nnzp, gidx, Mg, fs2, fn2, h2, z);

    // ---- epilogue ----
    apred_kernel<<<dim3(64, 64), 256, 0, stream>>>(z, out);
}